// Round 8
// baseline (149.101 us; speedup 1.0000x reference)
//
#include <hip/hip_runtime.h>
#include <hip/hip_bf16.h>

// CausalSelfAttention quirk kernel: softmax over QUERY axis, scale sqrt(D_OUT)=32.
// w[q,k] = exp(S/32)/Z[k], Z[k] = sum_{q>=k} exp(S/32)  (per-COLUMN denominator).
// Pass A (k_cstat) computes Z and folds 1/Z into V; pass B (k_ctx) recomputes S
// tile-wise and does PV. 1/32*log2e folded into Q at the QKV epilogue.
// k_ctx (this round): LDS-FREE, BARRIER-FREE. K/V per head (512 KB) is L2-resident,
// so staging through LDS was pure overhead + forced barriers. Each 64-thread block
// is one independent wave owning 32 q-rows; K/V/Q fragments load directly from
// global in MFMA fragment layout. P stays in registers (exp2 + pack + shfl_xor).

typedef __attribute__((ext_vector_type(8))) short short8;
typedef __attribute__((ext_vector_type(4))) float floatx4;
typedef __attribute__((ext_vector_type(16))) float floatx16;

#define SS 2048
#define DIN 1024
#define DOUT 1024
#define NH 16
#define HD 64
#define QSCALE 0.04508422002778011f  // (1/32) * log2(e)

#define MFMA16(a,b,c) __builtin_amdgcn_mfma_f32_16x16x32_bf16((a),(b),(c),0,0,0)
#define MFMA32(a,b,c) __builtin_amdgcn_mfma_f32_32x32x16_bf16((a),(b),(c),0,0,0)
#define EXP2F(x) __builtin_amdgcn_exp2f(x)
#define SBAR() __builtin_amdgcn_s_barrier()
#define WAITV0() asm volatile("s_waitcnt vmcnt(0)" ::: "memory")
#define WAITV4() asm volatile("s_waitcnt vmcnt(4)" ::: "memory")
#define WAITV8() asm volatile("s_waitcnt vmcnt(8)" ::: "memory")

__device__ __forceinline__ void gl_lds16(const void* g, void* l) {
  __builtin_amdgcn_global_load_lds((const __attribute__((address_space(1))) void*)g,
                                   (__attribute__((address_space(3))) void*)l, 16, 0, 0);
}

// Stage an 8-row chunk `c` of a [*][64] bf16 tile (global row stride `stride` elems)
// into LDS at lds + c*512, linear dest. XOR-swizzle applied on the GLOBAL source
// slot so that LDS[r][slot s] holds global slot s^(r&7).
__device__ __forceinline__ void stage64(const __hip_bfloat16* __restrict__ src, int stride,
                                        __hip_bfloat16* lds, int c, int l) {
  int r = c * 8 + (l >> 3);
  int cc = ((l & 7) ^ ((l >> 3) & 7)) * 8;
  gl_lds16(src + (size_t)r * stride + cc, lds + c * 512);
}

// 16x16x32 fragment: row `row`, k-slot ks*4+(l>>4).
__device__ __forceinline__ short8 frag64(const __hip_bfloat16* lds, int row, int ks, int l) {
  return *(const short8*)&lds[row * 64 + (((ks * 4 + (l >> 4)) ^ (row & 7)) * 8)];
}

// ---- convert x fp32 -> bf16 ----
__global__ __launch_bounds__(256) void k_cvt_x(const float* __restrict__ x,
                                               __hip_bfloat16* __restrict__ xb) {
  size_t i = ((size_t)blockIdx.x * 256 + threadIdx.x) * 4;
  float4 v = *(const float4*)(x + i);
  union { __hip_bfloat16 h[4]; short4 s; } u;
  u.h[0] = __float2bfloat16(v.x); u.h[1] = __float2bfloat16(v.y);
  u.h[2] = __float2bfloat16(v.z); u.h[3] = __float2bfloat16(v.w);
  *(short4*)(xb + i) = u.s;
}

// ---- transpose + convert W [k][c] fp32 -> Wt [c][k] bf16 ----
__global__ void k_twb(const float* __restrict__ W, __hip_bfloat16* __restrict__ Wt) {
  __shared__ float t[32][33];
  int tx = threadIdx.x, ty = threadIdx.y;
  int k0 = blockIdx.y * 32, c0 = blockIdx.x * 32;
#pragma unroll
  for (int i = 0; i < 4; ++i)
    t[ty + 8*i][tx] = W[(size_t)(k0 + ty + 8*i) * DOUT + c0 + tx];
  __syncthreads();
#pragma unroll
  for (int i = 0; i < 4; ++i)
    Wt[(size_t)(c0 + ty + 8*i) * DIN + k0 + tx] = __float2bfloat16(t[tx][ty + 8*i]);
}

// ---- QKV GEMM, BK=64, double-buffered, swizzled LDS, counted-vmcnt pipeline.
// q (z=0, pre-scaled by QSCALE), k (z=1): [b][h][s][d] ; v (z=2): [b][h][d][s] ----
__global__ __launch_bounds__(256) void k_qkv(
    const __hip_bfloat16* __restrict__ xb,
    const __hip_bfloat16* __restrict__ wq, const __hip_bfloat16* __restrict__ wk,
    const __hip_bfloat16* __restrict__ wv,
    __hip_bfloat16* __restrict__ qb, __hip_bfloat16* __restrict__ kb,
    __hip_bfloat16* __restrict__ vb) {
  __shared__ __hip_bfloat16 smem[32768];  // A0|A1|B0|B1, 8192 elems each (64KB)

  const __hip_bfloat16* wt; __hip_bfloat16* outp;
  if (blockIdx.z == 0)      { wt = wq; outp = qb; }
  else if (blockIdx.z == 1) { wt = wk; outp = kb; }
  else                      { wt = wv; outp = vb; }

  const int tid = threadIdx.x, w = tid >> 6, l = tid & 63;
  const int row0 = blockIdx.y * 128, col0 = blockIdx.x * 128;
  const int mw = (w >> 1) * 64, nw = (w & 1) * 64;

  const floatx4 fz = {0.f, 0.f, 0.f, 0.f};
  floatx4 acc[4][4];
#pragma unroll
  for (int m = 0; m < 4; ++m)
#pragma unroll
    for (int n = 0; n < 4; ++n) acc[m][n] = fz;

#pragma unroll
  for (int i = 0; i < 4; ++i) {
    stage64(xb + (size_t)row0 * DIN, DIN, smem, w*4+i, l);
    stage64(wt + (size_t)col0 * DIN, DIN, smem + 16384, w*4+i, l);
  }

  for (int kt = 0; kt < 16; ++kt) {
    int cur = kt & 1;
    __hip_bfloat16* Ac = smem + cur * 8192;
    __hip_bfloat16* Bc = smem + 16384 + cur * 8192;
    if (kt < 15) {
      int kk = (kt + 1) * 64;
      __hip_bfloat16* An = smem + (cur ^ 1) * 8192;
      __hip_bfloat16* Bn = smem + 16384 + (cur ^ 1) * 8192;
#pragma unroll
      for (int i = 0; i < 4; ++i) {
        stage64(xb + (size_t)row0 * DIN + kk, DIN, An, w*4+i, l);
        stage64(wt + (size_t)col0 * DIN + kk, DIN, Bn, w*4+i, l);
      }
      WAITV8();   // own loads for tile kt done; kt+1's 8 stay in flight
    } else {
      WAITV0();
    }
    SBAR();       // all waves' loads for tile kt landed
    short8 a[4][2], b[4][2];
#pragma unroll
    for (int m = 0; m < 4; ++m)
#pragma unroll
      for (int ks = 0; ks < 2; ++ks)
        a[m][ks] = frag64(Ac, mw + m*16 + (l & 15), ks, l);
#pragma unroll
    for (int n = 0; n < 4; ++n)
#pragma unroll
      for (int ks = 0; ks < 2; ++ks)
        b[n][ks] = frag64(Bc, nw + n*16 + (l & 15), ks, l);
#pragma unroll
    for (int ks = 0; ks < 2; ++ks)
#pragma unroll
      for (int m = 0; m < 4; ++m)
#pragma unroll
        for (int n = 0; n < 4; ++n)
          acc[m][n] = MFMA16(a[m][ks], b[n][ks], acc[m][n]);
    SBAR();       // reads of buf[cur] done before next iter's issue overwrites it
  }

  if (blockIdx.z == 2) {
    // V: transpose through LDS (padded stride 136), then 16B coalesced stores.
    __hip_bfloat16* Vt2 = smem;
#pragma unroll
    for (int m = 0; m < 4; ++m)
#pragma unroll
      for (int n = 0; n < 4; ++n)
#pragma unroll
        for (int r4 = 0; r4 < 4; ++r4) {
          int r = mw + m*16 + ((l >> 4) << 2) + r4;
          int c = nw + n*16 + (l & 15);
          Vt2[c * 136 + r] = __float2bfloat16(acc[m][n][r4]);
        }
    __syncthreads();
    int bb2 = row0 >> 11, sbase = row0 & (SS - 1);
#pragma unroll
    for (int i = 0; i < 8; ++i) {
      int drow = (tid >> 4) + i * 16;
      int scol = (tid & 15) * 8;
      int colg = col0 + drow, hh = colg >> 6, d = colg & 63;
      *(short8*)(outp + (((size_t)bb2 * NH + hh) * HD + d) * SS + sbase + scol) =
          *(const short8*)&Vt2[drow * 136 + scol];
    }
  } else {
    float sc = (blockIdx.z == 0) ? QSCALE : 1.0f;
#pragma unroll
    for (int m = 0; m < 4; ++m)
#pragma unroll
      for (int n = 0; n < 4; ++n)
#pragma unroll
        for (int r4 = 0; r4 < 4; ++r4) {
          int row = row0 + mw + m*16 + ((l >> 4) << 2) + r4;
          int col = col0 + nw + n*16 + (l & 15);
          int bb2 = row >> 11, s = row & (SS - 1), hh = col >> 6, d = col & 63;
          outp[(((size_t)bb2 * NH + hh) * SS + s) * HD + d] =
              __float2bfloat16(acc[m][n][r4] * sc);
        }
  }
}

// ---- pass A: Z[k] = sum_{q>=k} exp2(S'), then scale V columns by 1/Z in place. ----
__global__ __launch_bounds__(256) void k_cstat(const __hip_bfloat16* __restrict__ qb,
                                               const __hip_bfloat16* __restrict__ kb,
                                               __hip_bfloat16* __restrict__ vtb) {
  __shared__ __hip_bfloat16 smem[20480];  // Kt 4096 | Qt0 8192 | Qt1 8192 (40KB)
  __shared__ float red[4][64];
  __shared__ float zl[64];
  __hip_bfloat16* Kt = smem;
  const int bh = blockIdx.x;
  const int tid = threadIdx.x, w = tid >> 6, l = tid & 63;

  for (int jj = 0; jj < 2; ++jj) {
    int j = jj ? (31 - (int)blockIdx.y) : (int)blockIdx.y;
    int k0 = j * 64;
    int t0 = k0 >> 7, niter = 16 - t0;

#pragma unroll
    for (int i = 0; i < 2; ++i)
      stage64(kb + ((size_t)bh * SS + k0) * HD, HD, Kt, w*2+i, l);
#pragma unroll
    for (int i = 0; i < 4; ++i)
      stage64(qb + ((size_t)bh * SS + (t0 << 7)) * HD, HD, smem + 4096, w*4+i, l);

    short8 kf[4][2];
    float csum[4] = {0.f, 0.f, 0.f, 0.f};
    for (int it = 0; it < niter; ++it) {
      int cur = it & 1;
      __hip_bfloat16* Qc = smem + 4096 + cur * 8192;
      int q0 = (t0 + it) << 7;
      if (it + 1 < niter) {
        __hip_bfloat16* Qn = smem + 4096 + (cur ^ 1) * 8192;
#pragma unroll
        for (int i = 0; i < 4; ++i)
          stage64(qb + ((size_t)bh * SS + q0 + 128) * HD, HD, Qn, w*4+i, l);
        WAITV4();   // K + Q(it) done; Q(it+1)'s 4 in flight
      } else {
        WAITV0();
      }
      SBAR();
      if (it == 0) {
#pragma unroll
        for (int n = 0; n < 4; ++n)
#pragma unroll
          for (int ks = 0; ks < 2; ++ks)
            kf[n][ks] = frag64(Kt, n*16 + (l & 15), ks, l);
      }
      int qw = q0 + w * 32;
      if (qw + 31 >= k0) {
        short8 qa[2][2];
#pragma unroll
        for (int mm = 0; mm < 2; ++mm)
#pragma unroll
          for (int ks = 0; ks < 2; ++ks)
            qa[mm][ks] = frag64(Qc, w*32 + mm*16 + (l & 15), ks, l);
        floatx4 s[2][4];
#pragma unroll
        for (int mm = 0; mm < 2; ++mm)
#pragma unroll
          for (int n = 0; n < 4; ++n) {
            floatx4 t = {0.f, 0.f, 0.f, 0.f};
#pragma unroll
            for (int ks = 0; ks < 2; ++ks) t = MFMA16(qa[mm][ks], kf[n][ks], t);
            s[mm][n] = t;
          }
        bool dia = (k0 + 63 > qw);
#pragma unroll
        for (int mm = 0; mm < 2; ++mm)
#pragma unroll
          for (int n = 0; n < 4; ++n)
#pragma unroll
            for (int r4 = 0; r4 < 4; ++r4) {
              float e = EXP2F(s[mm][n][r4]);
              if (dia) {
                int q = qw + mm*16 + ((l >> 4) << 2) + r4;
                int k = k0 + n*16 + (l & 15);
                if (k > q) e = 0.f;
              }
              csum[n] += e;
            }
      }
      SBAR();
    }

#pragma unroll
    for (int n = 0; n < 4; ++n) {
      csum[n] += __shfl_xor(csum[n], 16);
      csum[n] += __shfl_xor(csum[n], 32);
      if (l < 16) red[w][n*16 + l] = csum[n];
    }
    __syncthreads();
    if (tid < 64)
      zl[tid] = 1.0f / (red[0][tid] + red[1][tid] + red[2][tid] + red[3][tid]);
    __syncthreads();
#pragma unroll
    for (int i = 0; i < 4; ++i) {
      int d = (tid >> 4) + i * 16;
      int c = (tid & 15) * 4;
      size_t base = ((size_t)bh * HD + d) * SS + k0 + c;
      short4 v = *(const short4*)(vtb + base);
      __hip_bfloat16* hp = (__hip_bfloat16*)&v;
#pragma unroll
      for (int jv = 0; jv < 4; ++jv)
        hp[jv] = __float2bfloat16(__bfloat162float(hp[jv]) * zl[c + jv]);
      *(short4*)(vtb + base) = v;
    }
    __syncthreads();
  }
}

// ---- pass B: ctx[q,:] = sum_{k<=q} exp2(S') * Vs[k,:]  (Vs has 1/Z folded).
// LDS-free, barrier-free: one wave (64 thr) per block, 32 q-rows each. Fragments
// load directly from global (K/V are L2-resident, 512KB/head; bh = j&31 keeps 4
// heads per XCD -> 2MB L2 working set). Swapped QK^T (32x32x16): lane holds
// P[q=lane&31][32 k] in regs; PV A-frags via pack+shfl_xor(32). Blocks sorted
// longest-first (qt = 63 - j/32) for tail balance.
__global__ __launch_bounds__(64) void k_ctx(const __hip_bfloat16* __restrict__ qb,
                                            const __hip_bfloat16* __restrict__ kb,
                                            const __hip_bfloat16* __restrict__ vtb,
                                            float* __restrict__ outp) {
  const int j = blockIdx.x;
  const int bh = j & 31, bb = bh >> 4, h = bh & 15;
  const int qt = 63 - (j >> 5);        // 0..63, longest tiles first
  const int l = threadIdx.x;
  const int hi = l >> 5;
  const int q0w = qt * 32;
  const int nkt = (qt >> 1) + 1;

  // Q fragments: lane q-row = q0w + (l&31), elems d = hc*16 + hi*8 .. +7.
  short8 qf[4];
  {
    const __hip_bfloat16* qrow = qb + ((size_t)bh * SS + q0w + (l & 31)) * HD + hi * 8;
#pragma unroll
    for (int hc = 0; hc < 4; ++hc)
      qf[hc] = *(const short8*)(qrow + hc * 16);
  }

  const __hip_bfloat16* kbase = kb + ((size_t)bh * SS + (l & 31)) * HD + hi * 8;
  const __hip_bfloat16* vbase = vtb + ((size_t)bh * HD + (l & 31)) * SS + hi * 8;

  const floatx16 fz16 = {0,0,0,0,0,0,0,0,0,0,0,0,0,0,0,0};
  floatx16 acc[2];
  acc[0] = fz16; acc[1] = fz16;

  for (int kt = 0; kt < nkt; ++kt) {
    const int k0 = kt << 6;
    // K fragments: A-rows k = k0 + 32H + (l&31), elems d = hc*16 + hi*8.
    short8 kf[2][4];
#pragma unroll
    for (int H = 0; H < 2; ++H)
#pragma unroll
      for (int hc = 0; hc < 4; ++hc)
        kf[H][hc] = *(const short8*)(kbase + (size_t)(k0 + H * 32) * HD + hc * 16);
    // V fragments: B-rows d = dn*32 + (l&31), elems k = k0 + ks*16 + hi*8.
    short8 vf[2][4];
#pragma unroll
    for (int dn = 0; dn < 2; ++dn)
#pragma unroll
      for (int ks = 0; ks < 4; ++ks)
        vf[dn][ks] = *(const short8*)(vbase + (size_t)dn * 32 * SS + k0 + ks * 16);

    // ST halves: ST[k0+32H+roff][q], roff = (r&3)+8*(r>>2)+4*hi
    floatx16 st[2];
#pragma unroll
    for (int H = 0; H < 2; ++H) {
      floatx16 t = fz16;
#pragma unroll
      for (int hc = 0; hc < 4; ++hc)
        t = MFMA32(kf[H][hc], qf[hc], t);
      st[H] = t;
    }
    // exp2 + causal mask + pack to bf16 pairs: pk[H][m][pr] holds
    // k = k0 + 32H + 8m + 4hi + 2pr + {0,1}
    const bool dia = (k0 + 63 > q0w);
    const int qg = q0w + (l & 31);
    unsigned pk[2][4][2];
#pragma unroll
    for (int H = 0; H < 2; ++H)
#pragma unroll
      for (int m = 0; m < 4; ++m)
#pragma unroll
        for (int pr = 0; pr < 2; ++pr) {
          float e0 = EXP2F(st[H][m*4 + pr*2]);
          float e1 = EXP2F(st[H][m*4 + pr*2 + 1]);
          if (dia) {
            int kb0 = k0 + H*32 + m*8 + hi*4 + pr*2;
            if (kb0 > qg)     e0 = 0.f;
            if (kb0 + 1 > qg) e1 = 0.f;
          }
          pk[H][m][pr] = (unsigned)__bfloat16_as_ushort(__float2bfloat16(e0)) |
                         ((unsigned)__bfloat16_as_ushort(__float2bfloat16(e1)) << 16);
        }
    // PV: 4 k-chunks of 16; A-frag k = 16ks + hi*8 + 0..7.
#pragma unroll
    for (int ks = 0; ks < 4; ++ks) {
      const int H = ks >> 1, mb = (ks & 1) * 2;
      unsigned keep0 = hi ? pk[H][mb+1][0] : pk[H][mb][0];
      unsigned keep1 = hi ? pk[H][mb+1][1] : pk[H][mb][1];
      unsigned send0 = hi ? pk[H][mb][0]   : pk[H][mb+1][0];
      unsigned send1 = hi ? pk[H][mb][1]   : pk[H][mb+1][1];
      unsigned recv0 = (unsigned)__shfl_xor((int)send0, 32);
      unsigned recv1 = (unsigned)__shfl_xor((int)send1, 32);
      union { unsigned u[4]; short8 s; } pa;
      pa.u[0] = hi ? recv0 : keep0;
      pa.u[1] = hi ? recv1 : keep1;
      pa.u[2] = hi ? keep0 : recv0;
      pa.u[3] = hi ? keep1 : recv1;
#pragma unroll
      for (int dn = 0; dn < 2; ++dn)
        acc[dn] = MFMA32(pa.s, vf[dn][ks], acc[dn]);
    }
  }

#pragma unroll
  for (int dn = 0; dn < 2; ++dn)
#pragma unroll
    for (int r = 0; r < 16; ++r) {
      int q = q0w + (r & 3) + 8*(r >> 2) + 4*hi;
      outp[((size_t)bb * SS + q) * DOUT + h * HD + dn*32 + (l & 31)] = acc[dn][r];
    }
}

extern "C" void kernel_launch(void* const* d_in, const int* in_sizes, int n_in,
                              void* d_out, int out_size, void* d_ws, size_t ws_size,
                              hipStream_t stream) {
  const float* x  = (const float*)d_in[0];
  const float* Wq = (const float*)d_in[1];
  const float* Wk = (const float*)d_in[2];
  const float* Wv = (const float*)d_in[3];
  float* out = (float*)d_out;
  char* ws = (char*)d_ws;

  __hip_bfloat16* xb  = (__hip_bfloat16*)(ws);                   // 8 MB
  __hip_bfloat16* wtq = (__hip_bfloat16*)(ws + (8ull  << 20));   // 2 MB
  __hip_bfloat16* wtk = (__hip_bfloat16*)(ws + (10ull << 20));   // 2 MB
  __hip_bfloat16* wtv = (__hip_bfloat16*)(ws + (12ull << 20));   // 2 MB
  __hip_bfloat16* qb  = (__hip_bfloat16*)(ws + (14ull << 20));   // 8 MB [b][h][s][d], pre-scaled
  __hip_bfloat16* kb  = (__hip_bfloat16*)(ws + (22ull << 20));   // 8 MB [b][h][s][d]
  __hip_bfloat16* vtb = (__hip_bfloat16*)(ws + (30ull << 20));   // 8 MB [b][h][d][s], 1/Z folded

  k_cvt_x<<<4096, 256, 0, stream>>>(x, xb);
  dim3 tb(32, 8);
  k_twb<<<dim3(32, 32), tb, 0, stream>>>(Wq, wtq);
  k_twb<<<dim3(32, 32), tb, 0, stream>>>(Wk, wtk);
  k_twb<<<dim3(32, 32), tb, 0, stream>>>(Wv, wtv);
  k_qkv<<<dim3(8, 32, 3), 256, 0, stream>>>(xb, wtq, wtk, wtv, qb, kb, vtb);
  k_cstat<<<dim3(32, 16), 256, 0, stream>>>(qb, kb, vtb);
  k_ctx<<<dim3(2048), 64, 0, stream>>>(qb, kb, vtb, out);
}

// Round 9
// 125.124 us; speedup vs baseline: 1.1916x; 1.1916x over previous
//
#include <hip/hip_runtime.h>
#include <hip/hip_bf16.h>

// CausalSelfAttention quirk kernel: softmax over QUERY axis, scale sqrt(D_OUT)=32.
// w[q,k] = exp(S/32)/Z[k], Z[k] = sum_{q>=k} exp(S/32)  (per-COLUMN denominator).
// Pass A (k_cstat) computes Z and folds 1/Z into V; pass B (k_ctx) recomputes S
// tile-wise and does PV. 1/32*log2e folded into Q at the QKV epilogue.
// k_ctx (this round): STRIDED q-row assignment. 512 blocks x 4 waves; block
// covers 128 contiguous q-rows [Q0,Q0+128); wave w owns rows Q0+w+4c -> every
// wave has the SAME causal k-range (no masked-idle waves), 32KB LDS -> 4
// blocks/CU = 16 all-active waves/CU. K/V staged to LDS (traffic amplification:
// round-8 showed direct-L2 reads cost 64x re-read = L3-bound, 75us).

typedef __attribute__((ext_vector_type(8))) short short8;
typedef __attribute__((ext_vector_type(4))) float floatx4;
typedef __attribute__((ext_vector_type(16))) float floatx16;

#define SS 2048
#define DIN 1024
#define DOUT 1024
#define NH 16
#define HD 64
#define QSCALE 0.04508422002778011f  // (1/32) * log2(e)

#define MFMA16(a,b,c) __builtin_amdgcn_mfma_f32_16x16x32_bf16((a),(b),(c),0,0,0)
#define MFMA32(a,b,c) __builtin_amdgcn_mfma_f32_32x32x16_bf16((a),(b),(c),0,0,0)
#define EXP2F(x) __builtin_amdgcn_exp2f(x)
#define SBAR() __builtin_amdgcn_s_barrier()
#define WAITV0() asm volatile("s_waitcnt vmcnt(0)" ::: "memory")
#define WAITV4() asm volatile("s_waitcnt vmcnt(4)" ::: "memory")
#define WAITV8() asm volatile("s_waitcnt vmcnt(8)" ::: "memory")

__device__ __forceinline__ void gl_lds16(const void* g, void* l) {
  __builtin_amdgcn_global_load_lds((const __attribute__((address_space(1))) void*)g,
                                   (__attribute__((address_space(3))) void*)l, 16, 0, 0);
}

// Stage an 8-row chunk `c` of a [*][64] bf16 tile (global row stride `stride` elems)
// into LDS at lds + c*512, linear dest. XOR-swizzle applied on the GLOBAL source
// slot so that LDS[r][slot s] holds global slot s^(r&7).
__device__ __forceinline__ void stage64(const __hip_bfloat16* __restrict__ src, int stride,
                                        __hip_bfloat16* lds, int c, int l) {
  int r = c * 8 + (l >> 3);
  int cc = ((l & 7) ^ ((l >> 3) & 7)) * 8;
  gl_lds16(src + (size_t)r * stride + cc, lds + c * 512);
}

// 16x16x32 fragment: row `row`, k-slot ks*4+(l>>4).
__device__ __forceinline__ short8 frag64(const __hip_bfloat16* lds, int row, int ks, int l) {
  return *(const short8*)&lds[row * 64 + (((ks * 4 + (l >> 4)) ^ (row & 7)) * 8)];
}

// 32x32x16 fragment: row `row` (0..63), 16-wide k-chunk `subk` (0..3), elems
// k = subk*16 + (l>>5)*8 + 0..7.
__device__ __forceinline__ short8 frag32(const __hip_bfloat16* lds, int row, int subk, int l) {
  return *(const short8*)&lds[row * 64 + (((subk * 2 + (l >> 5)) ^ (row & 7)) * 8)];
}

// ---- convert x fp32 -> bf16 ----
__global__ __launch_bounds__(256) void k_cvt_x(const float* __restrict__ x,
                                               __hip_bfloat16* __restrict__ xb) {
  size_t i = ((size_t)blockIdx.x * 256 + threadIdx.x) * 4;
  float4 v = *(const float4*)(x + i);
  union { __hip_bfloat16 h[4]; short4 s; } u;
  u.h[0] = __float2bfloat16(v.x); u.h[1] = __float2bfloat16(v.y);
  u.h[2] = __float2bfloat16(v.z); u.h[3] = __float2bfloat16(v.w);
  *(short4*)(xb + i) = u.s;
}

// ---- transpose + convert W [k][c] fp32 -> Wt [c][k] bf16 ----
__global__ void k_twb(const float* __restrict__ W, __hip_bfloat16* __restrict__ Wt) {
  __shared__ float t[32][33];
  int tx = threadIdx.x, ty = threadIdx.y;
  int k0 = blockIdx.y * 32, c0 = blockIdx.x * 32;
#pragma unroll
  for (int i = 0; i < 4; ++i)
    t[ty + 8*i][tx] = W[(size_t)(k0 + ty + 8*i) * DOUT + c0 + tx];
  __syncthreads();
#pragma unroll
  for (int i = 0; i < 4; ++i)
    Wt[(size_t)(c0 + ty + 8*i) * DIN + k0 + tx] = __float2bfloat16(t[tx][ty + 8*i]);
}

// ---- QKV GEMM, BK=64, double-buffered, swizzled LDS, counted-vmcnt pipeline.
// q (z=0, pre-scaled by QSCALE), k (z=1): [b][h][s][d] ; v (z=2): [b][h][d][s] ----
__global__ __launch_bounds__(256) void k_qkv(
    const __hip_bfloat16* __restrict__ xb,
    const __hip_bfloat16* __restrict__ wq, const __hip_bfloat16* __restrict__ wk,
    const __hip_bfloat16* __restrict__ wv,
    __hip_bfloat16* __restrict__ qb, __hip_bfloat16* __restrict__ kb,
    __hip_bfloat16* __restrict__ vb) {
  __shared__ __hip_bfloat16 smem[32768];  // A0|A1|B0|B1, 8192 elems each (64KB)

  const __hip_bfloat16* wt; __hip_bfloat16* outp;
  if (blockIdx.z == 0)      { wt = wq; outp = qb; }
  else if (blockIdx.z == 1) { wt = wk; outp = kb; }
  else                      { wt = wv; outp = vb; }

  const int tid = threadIdx.x, w = tid >> 6, l = tid & 63;
  const int row0 = blockIdx.y * 128, col0 = blockIdx.x * 128;
  const int mw = (w >> 1) * 64, nw = (w & 1) * 64;

  const floatx4 fz = {0.f, 0.f, 0.f, 0.f};
  floatx4 acc[4][4];
#pragma unroll
  for (int m = 0; m < 4; ++m)
#pragma unroll
    for (int n = 0; n < 4; ++n) acc[m][n] = fz;

#pragma unroll
  for (int i = 0; i < 4; ++i) {
    stage64(xb + (size_t)row0 * DIN, DIN, smem, w*4+i, l);
    stage64(wt + (size_t)col0 * DIN, DIN, smem + 16384, w*4+i, l);
  }

  for (int kt = 0; kt < 16; ++kt) {
    int cur = kt & 1;
    __hip_bfloat16* Ac = smem + cur * 8192;
    __hip_bfloat16* Bc = smem + 16384 + cur * 8192;
    if (kt < 15) {
      int kk = (kt + 1) * 64;
      __hip_bfloat16* An = smem + (cur ^ 1) * 8192;
      __hip_bfloat16* Bn = smem + 16384 + (cur ^ 1) * 8192;
#pragma unroll
      for (int i = 0; i < 4; ++i) {
        stage64(xb + (size_t)row0 * DIN + kk, DIN, An, w*4+i, l);
        stage64(wt + (size_t)col0 * DIN + kk, DIN, Bn, w*4+i, l);
      }
      WAITV8();   // own loads for tile kt done; kt+1's 8 stay in flight
    } else {
      WAITV0();
    }
    SBAR();       // all waves' loads for tile kt landed
    short8 a[4][2], b[4][2];
#pragma unroll
    for (int m = 0; m < 4; ++m)
#pragma unroll
      for (int ks = 0; ks < 2; ++ks)
        a[m][ks] = frag64(Ac, mw + m*16 + (l & 15), ks, l);
#pragma unroll
    for (int n = 0; n < 4; ++n)
#pragma unroll
      for (int ks = 0; ks < 2; ++ks)
        b[n][ks] = frag64(Bc, nw + n*16 + (l & 15), ks, l);
#pragma unroll
    for (int ks = 0; ks < 2; ++ks)
#pragma unroll
      for (int m = 0; m < 4; ++m)
#pragma unroll
        for (int n = 0; n < 4; ++n)
          acc[m][n] = MFMA16(a[m][ks], b[n][ks], acc[m][n]);
    SBAR();       // reads of buf[cur] done before next iter's issue overwrites it
  }

  if (blockIdx.z == 2) {
    // V: transpose through LDS (padded stride 136), then 16B coalesced stores.
    __hip_bfloat16* Vt2 = smem;
#pragma unroll
    for (int m = 0; m < 4; ++m)
#pragma unroll
      for (int n = 0; n < 4; ++n)
#pragma unroll
        for (int r4 = 0; r4 < 4; ++r4) {
          int r = mw + m*16 + ((l >> 4) << 2) + r4;
          int c = nw + n*16 + (l & 15);
          Vt2[c * 136 + r] = __float2bfloat16(acc[m][n][r4]);
        }
    __syncthreads();
    int bb2 = row0 >> 11, sbase = row0 & (SS - 1);
#pragma unroll
    for (int i = 0; i < 8; ++i) {
      int drow = (tid >> 4) + i * 16;
      int scol = (tid & 15) * 8;
      int colg = col0 + drow, hh = colg >> 6, d = colg & 63;
      *(short8*)(outp + (((size_t)bb2 * NH + hh) * HD + d) * SS + sbase + scol) =
          *(const short8*)&Vt2[drow * 136 + scol];
    }
  } else {
    float sc = (blockIdx.z == 0) ? QSCALE : 1.0f;
#pragma unroll
    for (int m = 0; m < 4; ++m)
#pragma unroll
      for (int n = 0; n < 4; ++n)
#pragma unroll
        for (int r4 = 0; r4 < 4; ++r4) {
          int row = row0 + mw + m*16 + ((l >> 4) << 2) + r4;
          int col = col0 + nw + n*16 + (l & 15);
          int bb2 = row >> 11, s = row & (SS - 1), hh = col >> 6, d = col & 63;
          outp[(((size_t)bb2 * NH + hh) * SS + s) * HD + d] =
              __float2bfloat16(acc[m][n][r4] * sc);
        }
  }
}

// ---- pass A: Z[k] = sum_{q>=k} exp2(S'), then scale V columns by 1/Z in place. ----
__global__ __launch_bounds__(256) void k_cstat(const __hip_bfloat16* __restrict__ qb,
                                               const __hip_bfloat16* __restrict__ kb,
                                               __hip_bfloat16* __restrict__ vtb) {
  __shared__ __hip_bfloat16 smem[20480];  // Kt 4096 | Qt0 8192 | Qt1 8192 (40KB)
  __shared__ float red[4][64];
  __shared__ float zl[64];
  __hip_bfloat16* Kt = smem;
  const int bh = blockIdx.x;
  const int tid = threadIdx.x, w = tid >> 6, l = tid & 63;

  for (int jj = 0; jj < 2; ++jj) {
    int j = jj ? (31 - (int)blockIdx.y) : (int)blockIdx.y;
    int k0 = j * 64;
    int t0 = k0 >> 7, niter = 16 - t0;

#pragma unroll
    for (int i = 0; i < 2; ++i)
      stage64(kb + ((size_t)bh * SS + k0) * HD, HD, Kt, w*2+i, l);
#pragma unroll
    for (int i = 0; i < 4; ++i)
      stage64(qb + ((size_t)bh * SS + (t0 << 7)) * HD, HD, smem + 4096, w*4+i, l);

    short8 kf[4][2];
    float csum[4] = {0.f, 0.f, 0.f, 0.f};
    for (int it = 0; it < niter; ++it) {
      int cur = it & 1;
      __hip_bfloat16* Qc = smem + 4096 + cur * 8192;
      int q0 = (t0 + it) << 7;
      if (it + 1 < niter) {
        __hip_bfloat16* Qn = smem + 4096 + (cur ^ 1) * 8192;
#pragma unroll
        for (int i = 0; i < 4; ++i)
          stage64(qb + ((size_t)bh * SS + q0 + 128) * HD, HD, Qn, w*4+i, l);
        WAITV4();   // K + Q(it) done; Q(it+1)'s 4 in flight
      } else {
        WAITV0();
      }
      SBAR();
      if (it == 0) {
#pragma unroll
        for (int n = 0; n < 4; ++n)
#pragma unroll
          for (int ks = 0; ks < 2; ++ks)
            kf[n][ks] = frag64(Kt, n*16 + (l & 15), ks, l);
      }
      int qw = q0 + w * 32;
      if (qw + 31 >= k0) {
        short8 qa[2][2];
#pragma unroll
        for (int mm = 0; mm < 2; ++mm)
#pragma unroll
          for (int ks = 0; ks < 2; ++ks)
            qa[mm][ks] = frag64(Qc, w*32 + mm*16 + (l & 15), ks, l);
        floatx4 s[2][4];
#pragma unroll
        for (int mm = 0; mm < 2; ++mm)
#pragma unroll
          for (int n = 0; n < 4; ++n) {
            floatx4 t = {0.f, 0.f, 0.f, 0.f};
#pragma unroll
            for (int ks = 0; ks < 2; ++ks) t = MFMA16(qa[mm][ks], kf[n][ks], t);
            s[mm][n] = t;
          }
        bool dia = (k0 + 63 > qw);
#pragma unroll
        for (int mm = 0; mm < 2; ++mm)
#pragma unroll
          for (int n = 0; n < 4; ++n)
#pragma unroll
            for (int r4 = 0; r4 < 4; ++r4) {
              float e = EXP2F(s[mm][n][r4]);
              if (dia) {
                int q = qw + mm*16 + ((l >> 4) << 2) + r4;
                int k = k0 + n*16 + (l & 15);
                if (k > q) e = 0.f;
              }
              csum[n] += e;
            }
      }
      SBAR();
    }

#pragma unroll
    for (int n = 0; n < 4; ++n) {
      csum[n] += __shfl_xor(csum[n], 16);
      csum[n] += __shfl_xor(csum[n], 32);
      if (l < 16) red[w][n*16 + l] = csum[n];
    }
    __syncthreads();
    if (tid < 64)
      zl[tid] = 1.0f / (red[0][tid] + red[1][tid] + red[2][tid] + red[3][tid]);
    __syncthreads();
#pragma unroll
    for (int i = 0; i < 4; ++i) {
      int d = (tid >> 4) + i * 16;
      int c = (tid & 15) * 4;
      size_t base = ((size_t)bh * HD + d) * SS + k0 + c;
      short4 v = *(const short4*)(vtb + base);
      __hip_bfloat16* hp = (__hip_bfloat16*)&v;
#pragma unroll
      for (int jv = 0; jv < 4; ++jv)
        hp[jv] = __float2bfloat16(__bfloat162float(hp[jv]) * zl[c + jv]);
      *(short4*)(vtb + base) = v;
    }
    __syncthreads();
  }
}

// ---- pass B: ctx[q,:] = sum_{k<=q} exp2(S') * Vs[k,:]  (Vs has 1/Z folded).
// 512 blocks x 4 waves (256 thr). Block i: bh = i&31, tb = 15-(i>>5) (longest
// first), q-rows [Q0,Q0+128), Q0 = tb*128. Wave w owns rows Q0+w+4c (c=lane&31)
// -> all waves share the same k-range: no idle waves. Swapped QK^T (32x32x16):
// lane holds P[q=own col][32 k] in regs; PV A-frags via pack+shfl_xor(32).
// LDS: K dbuf 0|4096, V dbuf 8192|12288 elems (32KB) -> 4 blocks/CU.
__global__ __launch_bounds__(256, 4) void k_ctx(const __hip_bfloat16* __restrict__ qb,
                                                const __hip_bfloat16* __restrict__ kb,
                                                const __hip_bfloat16* __restrict__ vtb,
                                                float* __restrict__ outp) {
  __shared__ __hip_bfloat16 smem[16384];  // 32KB
  const int i = blockIdx.x;
  const int bh = i & 31, bb = bh >> 4, h = bh & 15;
  const int tb = 15 - (i >> 5);
  const int Q0 = tb * 128;
  const int tid = threadIdx.x, w = tid >> 6, l = tid & 63;
  const int hi = l >> 5;
  const int qg = Q0 + w + 4 * (l & 31);   // lane's q-row (ST column c = l&31)
  const int nkt = 2 * (tb + 1);

  // Q fragments: lane q-row = qg, elems d = hc*16 + hi*8 .. +7. Drain vmcnt in
  // the prologue so loop's counted waits only see staging ops.
  short8 qf[4];
  {
    const __hip_bfloat16* qrow = qb + ((size_t)bh * SS + qg) * HD + hi * 8;
#pragma unroll
    for (int hc = 0; hc < 4; ++hc)
      qf[hc] = *(const short8*)(qrow + hc * 16);
  }
  asm volatile("" :: "v"(qf[0]), "v"(qf[1]), "v"(qf[2]), "v"(qf[3]));
  WAITV0();

  // stage K0/V0 (2 chunks per wave each)
#pragma unroll
  for (int ii = 0; ii < 2; ++ii) {
    stage64(kb + (size_t)bh * SS * HD, HD, smem, w*2+ii, l);
    stage64(vtb + (size_t)bh * HD * SS, SS, smem + 8192, w*2+ii, l);
  }

  const floatx16 fz16 = {0,0,0,0,0,0,0,0,0,0,0,0,0,0,0,0};
  floatx16 acc[2];
  acc[0] = fz16; acc[1] = fz16;

  for (int kt = 0; kt < nkt; ++kt) {
    int cur = kt & 1;
    __hip_bfloat16* Kc = smem + cur * 4096;
    __hip_bfloat16* Vc = smem + 8192 + cur * 4096;
    int k0 = kt << 6;
    if (kt + 1 < nkt) {
      int kn = k0 + 64;
#pragma unroll
      for (int ii = 0; ii < 2; ++ii) {
        stage64(kb + ((size_t)bh * SS + kn) * HD, HD, smem + (cur^1) * 4096, w*2+ii, l);
        stage64(vtb + (size_t)bh * HD * SS + kn, SS, smem + 8192 + (cur^1) * 4096, w*2+ii, l);
      }
      WAITV4();   // tile kt's 4 landed; kt+1's 4 stay in flight
    } else {
      WAITV0();
    }
    SBAR();       // buf[cur] fully populated across all waves

    // ST halves: ST[k0+32H+roff][c], roff = (r&3)+8*(r>>2)+4*hi
    floatx16 st[2];
#pragma unroll
    for (int H = 0; H < 2; ++H) {
      floatx16 t = fz16;
#pragma unroll
      for (int hc = 0; hc < 4; ++hc)
        t = MFMA32(frag32(Kc, H*32 + (l & 31), hc, l), qf[hc], t);
      st[H] = t;
    }
    // exp2 + causal mask + pack to bf16 pairs: pk[H][m][pr] holds
    // k = k0 + 32H + 8m + 4hi + 2pr + {0,1}
    const bool dia = (k0 + 63 > Q0 + w);   // min q in wave = Q0 + w
    unsigned pk[2][4][2];
#pragma unroll
    for (int H = 0; H < 2; ++H)
#pragma unroll
      for (int m = 0; m < 4; ++m)
#pragma unroll
        for (int pr = 0; pr < 2; ++pr) {
          float e0 = EXP2F(st[H][m*4 + pr*2]);
          float e1 = EXP2F(st[H][m*4 + pr*2 + 1]);
          if (dia) {
            int kb0 = k0 + H*32 + m*8 + hi*4 + pr*2;
            if (kb0 > qg)     e0 = 0.f;
            if (kb0 + 1 > qg) e1 = 0.f;
          }
          pk[H][m][pr] = (unsigned)__bfloat16_as_ushort(__float2bfloat16(e0)) |
                         ((unsigned)__bfloat16_as_ushort(__float2bfloat16(e1)) << 16);
        }
    // PV: 4 k-chunks of 16; A-frag k = 16ks + hi*8 + 0..7.
#pragma unroll
    for (int ks = 0; ks < 4; ++ks) {
      const int H = ks >> 1, mb = (ks & 1) * 2;
      unsigned keep0 = hi ? pk[H][mb+1][0] : pk[H][mb][0];
      unsigned keep1 = hi ? pk[H][mb+1][1] : pk[H][mb][1];
      unsigned send0 = hi ? pk[H][mb][0]   : pk[H][mb+1][0];
      unsigned send1 = hi ? pk[H][mb][1]   : pk[H][mb+1][1];
      unsigned recv0 = (unsigned)__shfl_xor((int)send0, 32);
      unsigned recv1 = (unsigned)__shfl_xor((int)send1, 32);
      union { unsigned u[4]; short8 s; } pa;
      pa.u[0] = hi ? recv0 : keep0;
      pa.u[1] = hi ? recv1 : keep1;
      pa.u[2] = hi ? keep0 : recv0;
      pa.u[3] = hi ? keep1 : recv1;
#pragma unroll
      for (int dn = 0; dn < 2; ++dn)
        acc[dn] = MFMA32(pa.s, frag32(Vc, dn*32 + (l & 31), ks, l), acc[dn]);
    }
    SBAR();       // reads of buf[cur] done before next iter overwrites it
  }

#pragma unroll
  for (int dn = 0; dn < 2; ++dn)
#pragma unroll
    for (int r = 0; r < 16; ++r) {
      int q = Q0 + w + 4 * ((r & 3) + 8*(r >> 2) + 4*hi);
      outp[((size_t)bb * SS + q) * DOUT + h * HD + dn*32 + (l & 31)] = acc[dn][r];
    }
}

extern "C" void kernel_launch(void* const* d_in, const int* in_sizes, int n_in,
                              void* d_out, int out_size, void* d_ws, size_t ws_size,
                              hipStream_t stream) {
  const float* x  = (const float*)d_in[0];
  const float* Wq = (const float*)d_in[1];
  const float* Wk = (const float*)d_in[2];
  const float* Wv = (const float*)d_in[3];
  float* out = (float*)d_out;
  char* ws = (char*)d_ws;

  __hip_bfloat16* xb  = (__hip_bfloat16*)(ws);                   // 8 MB
  __hip_bfloat16* wtq = (__hip_bfloat16*)(ws + (8ull  << 20));   // 2 MB
  __hip_bfloat16* wtk = (__hip_bfloat16*)(ws + (10ull << 20));   // 2 MB
  __hip_bfloat16* wtv = (__hip_bfloat16*)(ws + (12ull << 20));   // 2 MB
  __hip_bfloat16* qb  = (__hip_bfloat16*)(ws + (14ull << 20));   // 8 MB [b][h][s][d], pre-scaled
  __hip_bfloat16* kb  = (__hip_bfloat16*)(ws + (22ull << 20));   // 8 MB [b][h][s][d]
  __hip_bfloat16* vtb = (__hip_bfloat16*)(ws + (30ull << 20));   // 8 MB [b][h][d][s], 1/Z folded

  k_cvt_x<<<4096, 256, 0, stream>>>(x, xb);
  dim3 tb(32, 8);
  k_twb<<<dim3(32, 32), tb, 0, stream>>>(Wq, wtq);
  k_twb<<<dim3(32, 32), tb, 0, stream>>>(Wk, wtk);
  k_twb<<<dim3(32, 32), tb, 0, stream>>>(Wv, wtv);
  k_qkv<<<dim3(8, 32, 3), 256, 0, stream>>>(xb, wtq, wtk, wtv, qb, kb, vtb);
  k_cstat<<<dim3(32, 16), 256, 0, stream>>>(qb, kb, vtb);
  k_ctx<<<dim3(512), 256, 0, stream>>>(qb, kb, vtb, out);
}

// Round 10
// 124.114 us; speedup vs baseline: 1.2013x; 1.0081x over previous
//
#include <hip/hip_runtime.h>
#include <hip/hip_bf16.h>

// CausalSelfAttention quirk kernel: softmax over QUERY axis, scale sqrt(D_OUT)=32.
// w[q,k] = exp(S/32)/Z[k], Z[k] = sum_{q>=k} exp(S/32)  (per-COLUMN denominator).
// Pass A (k_cstat) computes Z and folds 1/Z into V; pass B (k_ctx) recomputes S
// tile-wise and does PV. 1/32*log2e folded into Q at the QKV epilogue.
// k_ctx (this round): K-SPLIT x4. Fitted model from rounds 3-9: wall time =
// (longest wave's k-tile count) x ~3600 cyc, invariant to occupancy shuffles.
// Since 1/Z is folded into V, PV accumulation is LINEAR in k -> the k-range
// splits freely. 512 blocks x 16 waves: wave (g,s) = row-group g (rows Q0+g+4c),
// k-quarter s (tiles s, s+4, ...). Longest wave: 8 iters (was 32). Private
// K/V dbuf per quarter (128KB LDS); partials summed via LDS at the end.

typedef __attribute__((ext_vector_type(8))) short short8;
typedef __attribute__((ext_vector_type(4))) float floatx4;
typedef __attribute__((ext_vector_type(16))) float floatx16;

#define SS 2048
#define DIN 1024
#define DOUT 1024
#define NH 16
#define HD 64
#define QSCALE 0.04508422002778011f  // (1/32) * log2(e)

#define MFMA16(a,b,c) __builtin_amdgcn_mfma_f32_16x16x32_bf16((a),(b),(c),0,0,0)
#define MFMA32(a,b,c) __builtin_amdgcn_mfma_f32_32x32x16_bf16((a),(b),(c),0,0,0)
#define EXP2F(x) __builtin_amdgcn_exp2f(x)
#define SBAR() __builtin_amdgcn_s_barrier()
#define WAITV0() asm volatile("s_waitcnt vmcnt(0)" ::: "memory")
#define WAITV4() asm volatile("s_waitcnt vmcnt(4)" ::: "memory")
#define WAITV8() asm volatile("s_waitcnt vmcnt(8)" ::: "memory")

__device__ __forceinline__ void gl_lds16(const void* g, void* l) {
  __builtin_amdgcn_global_load_lds((const __attribute__((address_space(1))) void*)g,
                                   (__attribute__((address_space(3))) void*)l, 16, 0, 0);
}

// Stage an 8-row chunk `c` of a [*][64] bf16 tile (global row stride `stride` elems)
// into LDS at lds + c*512, linear dest. XOR-swizzle applied on the GLOBAL source
// slot so that LDS[r][slot s] holds global slot s^(r&7).
__device__ __forceinline__ void stage64(const __hip_bfloat16* __restrict__ src, int stride,
                                        __hip_bfloat16* lds, int c, int l) {
  int r = c * 8 + (l >> 3);
  int cc = ((l & 7) ^ ((l >> 3) & 7)) * 8;
  gl_lds16(src + (size_t)r * stride + cc, lds + c * 512);
}

// 16x16x32 fragment: row `row`, k-slot ks*4+(l>>4).
__device__ __forceinline__ short8 frag64(const __hip_bfloat16* lds, int row, int ks, int l) {
  return *(const short8*)&lds[row * 64 + (((ks * 4 + (l >> 4)) ^ (row & 7)) * 8)];
}

// 32x32x16 fragment: row `row` (0..63), 16-wide k-chunk `subk` (0..3), elems
// k = subk*16 + (l>>5)*8 + 0..7.
__device__ __forceinline__ short8 frag32(const __hip_bfloat16* lds, int row, int subk, int l) {
  return *(const short8*)&lds[row * 64 + (((subk * 2 + (l >> 5)) ^ (row & 7)) * 8)];
}

// ---- convert x fp32 -> bf16 ----
__global__ __launch_bounds__(256) void k_cvt_x(const float* __restrict__ x,
                                               __hip_bfloat16* __restrict__ xb) {
  size_t i = ((size_t)blockIdx.x * 256 + threadIdx.x) * 4;
  float4 v = *(const float4*)(x + i);
  union { __hip_bfloat16 h[4]; short4 s; } u;
  u.h[0] = __float2bfloat16(v.x); u.h[1] = __float2bfloat16(v.y);
  u.h[2] = __float2bfloat16(v.z); u.h[3] = __float2bfloat16(v.w);
  *(short4*)(xb + i) = u.s;
}

// ---- transpose + convert W [k][c] fp32 -> Wt [c][k] bf16 ----
__global__ void k_twb(const float* __restrict__ W, __hip_bfloat16* __restrict__ Wt) {
  __shared__ float t[32][33];
  int tx = threadIdx.x, ty = threadIdx.y;
  int k0 = blockIdx.y * 32, c0 = blockIdx.x * 32;
#pragma unroll
  for (int i = 0; i < 4; ++i)
    t[ty + 8*i][tx] = W[(size_t)(k0 + ty + 8*i) * DOUT + c0 + tx];
  __syncthreads();
#pragma unroll
  for (int i = 0; i < 4; ++i)
    Wt[(size_t)(c0 + ty + 8*i) * DIN + k0 + tx] = __float2bfloat16(t[tx][ty + 8*i]);
}

// ---- QKV GEMM, BK=64, double-buffered, swizzled LDS, counted-vmcnt pipeline.
// q (z=0, pre-scaled by QSCALE), k (z=1): [b][h][s][d] ; v (z=2): [b][h][d][s] ----
__global__ __launch_bounds__(256) void k_qkv(
    const __hip_bfloat16* __restrict__ xb,
    const __hip_bfloat16* __restrict__ wq, const __hip_bfloat16* __restrict__ wk,
    const __hip_bfloat16* __restrict__ wv,
    __hip_bfloat16* __restrict__ qb, __hip_bfloat16* __restrict__ kb,
    __hip_bfloat16* __restrict__ vb) {
  __shared__ __hip_bfloat16 smem[32768];  // A0|A1|B0|B1, 8192 elems each (64KB)

  const __hip_bfloat16* wt; __hip_bfloat16* outp;
  if (blockIdx.z == 0)      { wt = wq; outp = qb; }
  else if (blockIdx.z == 1) { wt = wk; outp = kb; }
  else                      { wt = wv; outp = vb; }

  const int tid = threadIdx.x, w = tid >> 6, l = tid & 63;
  const int row0 = blockIdx.y * 128, col0 = blockIdx.x * 128;
  const int mw = (w >> 1) * 64, nw = (w & 1) * 64;

  const floatx4 fz = {0.f, 0.f, 0.f, 0.f};
  floatx4 acc[4][4];
#pragma unroll
  for (int m = 0; m < 4; ++m)
#pragma unroll
    for (int n = 0; n < 4; ++n) acc[m][n] = fz;

#pragma unroll
  for (int i = 0; i < 4; ++i) {
    stage64(xb + (size_t)row0 * DIN, DIN, smem, w*4+i, l);
    stage64(wt + (size_t)col0 * DIN, DIN, smem + 16384, w*4+i, l);
  }

  for (int kt = 0; kt < 16; ++kt) {
    int cur = kt & 1;
    __hip_bfloat16* Ac = smem + cur * 8192;
    __hip_bfloat16* Bc = smem + 16384 + cur * 8192;
    if (kt < 15) {
      int kk = (kt + 1) * 64;
      __hip_bfloat16* An = smem + (cur ^ 1) * 8192;
      __hip_bfloat16* Bn = smem + 16384 + (cur ^ 1) * 8192;
#pragma unroll
      for (int i = 0; i < 4; ++i) {
        stage64(xb + (size_t)row0 * DIN + kk, DIN, An, w*4+i, l);
        stage64(wt + (size_t)col0 * DIN + kk, DIN, Bn, w*4+i, l);
      }
      WAITV8();   // own loads for tile kt done; kt+1's 8 stay in flight
    } else {
      WAITV0();
    }
    SBAR();       // all waves' loads for tile kt landed
    short8 a[4][2], b[4][2];
#pragma unroll
    for (int m = 0; m < 4; ++m)
#pragma unroll
      for (int ks = 0; ks < 2; ++ks)
        a[m][ks] = frag64(Ac, mw + m*16 + (l & 15), ks, l);
#pragma unroll
    for (int n = 0; n < 4; ++n)
#pragma unroll
      for (int ks = 0; ks < 2; ++ks)
        b[n][ks] = frag64(Bc, nw + n*16 + (l & 15), ks, l);
#pragma unroll
    for (int ks = 0; ks < 2; ++ks)
#pragma unroll
      for (int m = 0; m < 4; ++m)
#pragma unroll
        for (int n = 0; n < 4; ++n)
          acc[m][n] = MFMA16(a[m][ks], b[n][ks], acc[m][n]);
    SBAR();       // reads of buf[cur] done before next iter's issue overwrites it
  }

  if (blockIdx.z == 2) {
    // V: transpose through LDS (padded stride 136), then 16B coalesced stores.
    __hip_bfloat16* Vt2 = smem;
#pragma unroll
    for (int m = 0; m < 4; ++m)
#pragma unroll
      for (int n = 0; n < 4; ++n)
#pragma unroll
        for (int r4 = 0; r4 < 4; ++r4) {
          int r = mw + m*16 + ((l >> 4) << 2) + r4;
          int c = nw + n*16 + (l & 15);
          Vt2[c * 136 + r] = __float2bfloat16(acc[m][n][r4]);
        }
    __syncthreads();
    int bb2 = row0 >> 11, sbase = row0 & (SS - 1);
#pragma unroll
    for (int i = 0; i < 8; ++i) {
      int drow = (tid >> 4) + i * 16;
      int scol = (tid & 15) * 8;
      int colg = col0 + drow, hh = colg >> 6, d = colg & 63;
      *(short8*)(outp + (((size_t)bb2 * NH + hh) * HD + d) * SS + sbase + scol) =
          *(const short8*)&Vt2[drow * 136 + scol];
    }
  } else {
    float sc = (blockIdx.z == 0) ? QSCALE : 1.0f;
#pragma unroll
    for (int m = 0; m < 4; ++m)
#pragma unroll
      for (int n = 0; n < 4; ++n)
#pragma unroll
        for (int r4 = 0; r4 < 4; ++r4) {
          int row = row0 + mw + m*16 + ((l >> 4) << 2) + r4;
          int col = col0 + nw + n*16 + (l & 15);
          int bb2 = row >> 11, s = row & (SS - 1), hh = col >> 6, d = col & 63;
          outp[(((size_t)bb2 * NH + hh) * SS + s) * HD + d] =
              __float2bfloat16(acc[m][n][r4] * sc);
        }
  }
}

// ---- pass A: Z[k] = sum_{q>=k} exp2(S'), then scale V columns by 1/Z in place. ----
__global__ __launch_bounds__(256) void k_cstat(const __hip_bfloat16* __restrict__ qb,
                                               const __hip_bfloat16* __restrict__ kb,
                                               __hip_bfloat16* __restrict__ vtb) {
  __shared__ __hip_bfloat16 smem[20480];  // Kt 4096 | Qt0 8192 | Qt1 8192 (40KB)
  __shared__ float red[4][64];
  __shared__ float zl[64];
  __hip_bfloat16* Kt = smem;
  const int bh = blockIdx.x;
  const int tid = threadIdx.x, w = tid >> 6, l = tid & 63;

  for (int jj = 0; jj < 2; ++jj) {
    int j = jj ? (31 - (int)blockIdx.y) : (int)blockIdx.y;
    int k0 = j * 64;
    int t0 = k0 >> 7, niter = 16 - t0;

#pragma unroll
    for (int i = 0; i < 2; ++i)
      stage64(kb + ((size_t)bh * SS + k0) * HD, HD, Kt, w*2+i, l);
#pragma unroll
    for (int i = 0; i < 4; ++i)
      stage64(qb + ((size_t)bh * SS + (t0 << 7)) * HD, HD, smem + 4096, w*4+i, l);

    short8 kf[4][2];
    float csum[4] = {0.f, 0.f, 0.f, 0.f};
    for (int it = 0; it < niter; ++it) {
      int cur = it & 1;
      __hip_bfloat16* Qc = smem + 4096 + cur * 8192;
      int q0 = (t0 + it) << 7;
      if (it + 1 < niter) {
        __hip_bfloat16* Qn = smem + 4096 + (cur ^ 1) * 8192;
#pragma unroll
        for (int i = 0; i < 4; ++i)
          stage64(qb + ((size_t)bh * SS + q0 + 128) * HD, HD, Qn, w*4+i, l);
        WAITV4();   // K + Q(it) done; Q(it+1)'s 4 in flight
      } else {
        WAITV0();
      }
      SBAR();
      if (it == 0) {
#pragma unroll
        for (int n = 0; n < 4; ++n)
#pragma unroll
          for (int ks = 0; ks < 2; ++ks)
            kf[n][ks] = frag64(Kt, n*16 + (l & 15), ks, l);
      }
      int qw = q0 + w * 32;
      if (qw + 31 >= k0) {
        short8 qa[2][2];
#pragma unroll
        for (int mm = 0; mm < 2; ++mm)
#pragma unroll
          for (int ks = 0; ks < 2; ++ks)
            qa[mm][ks] = frag64(Qc, w*32 + mm*16 + (l & 15), ks, l);
        floatx4 s[2][4];
#pragma unroll
        for (int mm = 0; mm < 2; ++mm)
#pragma unroll
          for (int n = 0; n < 4; ++n) {
            floatx4 t = {0.f, 0.f, 0.f, 0.f};
#pragma unroll
            for (int ks = 0; ks < 2; ++ks) t = MFMA16(qa[mm][ks], kf[n][ks], t);
            s[mm][n] = t;
          }
        bool dia = (k0 + 63 > qw);
#pragma unroll
        for (int mm = 0; mm < 2; ++mm)
#pragma unroll
          for (int n = 0; n < 4; ++n)
#pragma unroll
            for (int r4 = 0; r4 < 4; ++r4) {
              float e = EXP2F(s[mm][n][r4]);
              if (dia) {
                int q = qw + mm*16 + ((l >> 4) << 2) + r4;
                int k = k0 + n*16 + (l & 15);
                if (k > q) e = 0.f;
              }
              csum[n] += e;
            }
      }
      SBAR();
    }

#pragma unroll
    for (int n = 0; n < 4; ++n) {
      csum[n] += __shfl_xor(csum[n], 16);
      csum[n] += __shfl_xor(csum[n], 32);
      if (l < 16) red[w][n*16 + l] = csum[n];
    }
    __syncthreads();
    if (tid < 64)
      zl[tid] = 1.0f / (red[0][tid] + red[1][tid] + red[2][tid] + red[3][tid]);
    __syncthreads();
#pragma unroll
    for (int i = 0; i < 4; ++i) {
      int d = (tid >> 4) + i * 16;
      int c = (tid & 15) * 4;
      size_t base = ((size_t)bh * HD + d) * SS + k0 + c;
      short4 v = *(const short4*)(vtb + base);
      __hip_bfloat16* hp = (__hip_bfloat16*)&v;
#pragma unroll
      for (int jv = 0; jv < 4; ++jv)
        hp[jv] = __float2bfloat16(__bfloat162float(hp[jv]) * zl[c + jv]);
      *(short4*)(vtb + base) = v;
    }
    __syncthreads();
  }
}

// ---- pass B: ctx[q,:] = sum_{k<=q} exp2(S') * Vs[k,:]  (Vs has 1/Z folded).
// K-SPLIT x4: 512 blocks x 16 waves (1024 thr). Block i: bh = i&31,
// tb = (i<256) ? 15-(i>>5) : (i-256)>>5 (big+small pair per CU, sum = 15).
// Wave w: row-group g = w&3 (rows Q0+g+4c, c=lane&31), k-quarter s = w>>2
// (k-tiles s, s+4, ...). Private K/V dbuf per quarter: smem + s*16384
// [K0|K1|V0|V1 x 4096 elems] = 128KB total. Partials: s>0 waves dump acc to
// LDS (aliases staging), s=0 adds and stores.
__global__ __launch_bounds__(1024, 4) void k_ctx(const __hip_bfloat16* __restrict__ qb,
                                                 const __hip_bfloat16* __restrict__ kb,
                                                 const __hip_bfloat16* __restrict__ vtb,
                                                 float* __restrict__ outp) {
  __shared__ __hip_bfloat16 smem[65536];  // 128KB
  const int i = blockIdx.x;
  const int bh = i & 31, bb = bh >> 4, h = bh & 15;
  const int tb = (i < 256) ? (15 - (i >> 5)) : ((i - 256) >> 5);
  const int Q0 = tb * 128;
  const int tid = threadIdx.x, w = tid >> 6, l = tid & 63;
  const int g = w & 3, s = w >> 2;
  const int hi = l >> 5;
  const int qg = Q0 + g + 4 * (l & 31);   // lane's q-row (ST column c = l&31)
  const int nkt = 2 * (tb + 1);           // 64-wide k-tiles in causal range
  const int nit = (nkt + 3) >> 2;         // loop count (uniform across waves)
  __hip_bfloat16* qsm = smem + s * 16384; // quarter's region: K0|K1|V0|V1

  // Q fragments: lane q-row = qg, elems d = hc*16 + hi*8 .. +7. Drain vmcnt in
  // the prologue so loop's counted waits only see staging ops.
  short8 qf[4];
  {
    const __hip_bfloat16* qrow = qb + ((size_t)bh * SS + qg) * HD + hi * 8;
#pragma unroll
    for (int hc = 0; hc < 4; ++hc)
      qf[hc] = *(const short8*)(qrow + hc * 16);
  }
  asm volatile("" :: "v"(qf[0]), "v"(qf[1]), "v"(qf[2]), "v"(qf[3]));
  WAITV0();

  // stage quarter's first k-tile (index s), 2 K-chunks + 2 V-chunks per wave
  if (s < nkt) {
    int kn = s << 6;
#pragma unroll
    for (int ii = 0; ii < 2; ++ii) {
      stage64(kb + ((size_t)bh * SS + kn) * HD, HD, qsm, g*2+ii, l);
      stage64(vtb + (size_t)bh * HD * SS + kn, SS, qsm + 8192, g*2+ii, l);
    }
  }

  const floatx16 fz16 = {0,0,0,0,0,0,0,0,0,0,0,0,0,0,0,0};
  floatx16 acc[2];
  acc[0] = fz16; acc[1] = fz16;

  for (int it = 0; it < nit; ++it) {
    int cur = it & 1;
    __hip_bfloat16* Kc = qsm + cur * 4096;
    __hip_bfloat16* Vc = qsm + 8192 + cur * 4096;
    const int myk = s + 4 * it;
    const int nxt = myk + 4;
    if (nxt < nkt) {
      int kn = nxt << 6;
#pragma unroll
      for (int ii = 0; ii < 2; ++ii) {
        stage64(kb + ((size_t)bh * SS + kn) * HD, HD, qsm + (cur^1) * 4096, g*2+ii, l);
        stage64(vtb + (size_t)bh * HD * SS + kn, SS, qsm + 8192 + (cur^1) * 4096, g*2+ii, l);
      }
      WAITV4();   // tile myk's 4 landed; nxt's 4 stay in flight
    } else {
      WAITV0();
    }
    SBAR();       // quarter's buf[cur] fully populated (its 4 waves all past wait)

    if (myk < nkt) {
      const int k0 = myk << 6;
      // ST halves: ST[k0+32H+roff][c], roff = (r&3)+8*(r>>2)+4*hi
      floatx16 st[2];
#pragma unroll
      for (int H = 0; H < 2; ++H) {
        floatx16 t = fz16;
#pragma unroll
        for (int hc = 0; hc < 4; ++hc)
          t = MFMA32(frag32(Kc, H*32 + (l & 31), hc, l), qf[hc], t);
        st[H] = t;
      }
      // exp2 + causal mask + pack to bf16 pairs: pk[H][m][pr] holds
      // k = k0 + 32H + 8m + 4hi + 2pr + {0,1}
      const bool dia = (k0 + 63 > Q0 + g);   // min q in wave = Q0 + g
      unsigned pk[2][4][2];
#pragma unroll
      for (int H = 0; H < 2; ++H)
#pragma unroll
        for (int m = 0; m < 4; ++m)
#pragma unroll
          for (int pr = 0; pr < 2; ++pr) {
            float e0 = EXP2F(st[H][m*4 + pr*2]);
            float e1 = EXP2F(st[H][m*4 + pr*2 + 1]);
            if (dia) {
              int kb0 = k0 + H*32 + m*8 + hi*4 + pr*2;
              if (kb0 > qg)     e0 = 0.f;
              if (kb0 + 1 > qg) e1 = 0.f;
            }
            pk[H][m][pr] = (unsigned)__bfloat16_as_ushort(__float2bfloat16(e0)) |
                           ((unsigned)__bfloat16_as_ushort(__float2bfloat16(e1)) << 16);
          }
      // PV: 4 k-chunks of 16; A-frag k = 16ks + hi*8 + 0..7.
#pragma unroll
      for (int ks = 0; ks < 4; ++ks) {
        const int H = ks >> 1, mb = (ks & 1) * 2;
        unsigned keep0 = hi ? pk[H][mb+1][0] : pk[H][mb][0];
        unsigned keep1 = hi ? pk[H][mb+1][1] : pk[H][mb][1];
        unsigned send0 = hi ? pk[H][mb][0]   : pk[H][mb+1][0];
        unsigned send1 = hi ? pk[H][mb][1]   : pk[H][mb+1][1];
        unsigned recv0 = (unsigned)__shfl_xor((int)send0, 32);
        unsigned recv1 = (unsigned)__shfl_xor((int)send1, 32);
        union { unsigned u[4]; short8 sv; } pa;
        pa.u[0] = hi ? recv0 : keep0;
        pa.u[1] = hi ? recv1 : keep1;
        pa.u[2] = hi ? keep0 : recv0;
        pa.u[3] = hi ? keep1 : recv1;
#pragma unroll
        for (int dn = 0; dn < 2; ++dn)
          acc[dn] = MFMA32(pa.sv, frag32(Vc, dn*32 + (l & 31), ks, l), acc[dn]);
      }
    }
    SBAR();       // reads of buf[cur] done before next iter overwrites it
  }

  // ---- reduce partials across k-quarters: acc_final[g] = sum_s acc[g][s] ----
  float* fsm = (float*)smem;   // staging dead after final SBAR; 32768 floats
  if (s > 0) {
    float* dst = fsm + ((s - 1) * 4 + g) * 2048;
#pragma unroll
    for (int dn = 0; dn < 2; ++dn)
#pragma unroll
      for (int r = 0; r < 16; ++r)
        dst[(dn * 16 + r) * 64 + l] = acc[dn][r];
  }
  __syncthreads();
  if (s == 0) {
#pragma unroll
    for (int sp = 0; sp < 3; ++sp) {
      const float* src = fsm + (sp * 4 + g) * 2048;
#pragma unroll
      for (int dn = 0; dn < 2; ++dn)
#pragma unroll
        for (int r = 0; r < 16; ++r)
          acc[dn][r] += src[(dn * 16 + r) * 64 + l];
    }
#pragma unroll
    for (int dn = 0; dn < 2; ++dn)
#pragma unroll
      for (int r = 0; r < 16; ++r) {
        int q = Q0 + g + 4 * ((r & 3) + 8*(r >> 2) + 4*hi);
        outp[((size_t)bb * SS + q) * DOUT + h * HD + dn*32 + (l & 31)] = acc[dn][r];
      }
  }
}

extern "C" void kernel_launch(void* const* d_in, const int* in_sizes, int n_in,
                              void* d_out, int out_size, void* d_ws, size_t ws_size,
                              hipStream_t stream) {
  const float* x  = (const float*)d_in[0];
  const float* Wq = (const float*)d_in[1];
  const float* Wk = (const float*)d_in[2];
  const float* Wv = (const float*)d_in[3];
  float* out = (float*)d_out;
  char* ws = (char*)d_ws;

  __hip_bfloat16* xb  = (__hip_bfloat16*)(ws);                   // 8 MB
  __hip_bfloat16* wtq = (__hip_bfloat16*)(ws + (8ull  << 20));   // 2 MB
  __hip_bfloat16* wtk = (__hip_bfloat16*)(ws + (10ull << 20));   // 2 MB
  __hip_bfloat16* wtv = (__hip_bfloat16*)(ws + (12ull << 20));   // 2 MB
  __hip_bfloat16* qb  = (__hip_bfloat16*)(ws + (14ull << 20));   // 8 MB [b][h][s][d], pre-scaled
  __hip_bfloat16* kb  = (__hip_bfloat16*)(ws + (22ull << 20));   // 8 MB [b][h][s][d]
  __hip_bfloat16* vtb = (__hip_bfloat16*)(ws + (30ull << 20));   // 8 MB [b][h][d][s], 1/Z folded

  k_cvt_x<<<4096, 256, 0, stream>>>(x, xb);
  dim3 tb(32, 8);
  k_twb<<<dim3(32, 32), tb, 0, stream>>>(Wq, wtq);
  k_twb<<<dim3(32, 32), tb, 0, stream>>>(Wk, wtk);
  k_twb<<<dim3(32, 32), tb, 0, stream>>>(Wv, wtv);
  k_qkv<<<dim3(8, 32, 3), 256, 0, stream>>>(xb, wtq, wtk, wtv, qb, kb, vtb);
  k_cstat<<<dim3(32, 16), 256, 0, stream>>>(qb, kb, vtb);
  k_ctx<<<dim3(512), 1024, 0, stream>>>(qb, kb, vtb, out);
}

// Round 11
// 114.724 us; speedup vs baseline: 1.2996x; 1.0818x over previous
//
#include <hip/hip_runtime.h>
#include <hip/hip_bf16.h>

// CausalSelfAttention quirk kernel: softmax over QUERY axis, scale sqrt(D_OUT)=32.
// w[q,k] = exp(S/32)/Z[k], Z[k] = sum_{q>=k} exp(S/32)  (per-COLUMN denominator).
// Pass A (k_cstat) computes Z and folds 1/Z into V; pass B (k_ctx) recomputes S
// tile-wise and does PV. 1/32*log2e folded into Q at the QKV epilogue.
// Round 11: k_ctx kept as-is (7 structural variants all ~49us; stop shuffling).
// k_cstat: one j per block, 1024 blocks, 3/CU co-resident (was 2 serial jobs).
// k_qkv: Q/K epilogue repacked through LDS for 16B coalesced stores (was 2B
// scalar). k_twb merged into one z-indexed launch.

typedef __attribute__((ext_vector_type(8))) short short8;
typedef __attribute__((ext_vector_type(4))) float floatx4;
typedef __attribute__((ext_vector_type(16))) float floatx16;

#define SS 2048
#define DIN 1024
#define DOUT 1024
#define NH 16
#define HD 64
#define QSCALE 0.04508422002778011f  // (1/32) * log2(e)

#define MFMA16(a,b,c) __builtin_amdgcn_mfma_f32_16x16x32_bf16((a),(b),(c),0,0,0)
#define MFMA32(a,b,c) __builtin_amdgcn_mfma_f32_32x32x16_bf16((a),(b),(c),0,0,0)
#define EXP2F(x) __builtin_amdgcn_exp2f(x)
#define SBAR() __builtin_amdgcn_s_barrier()
#define WAITV0() asm volatile("s_waitcnt vmcnt(0)" ::: "memory")
#define WAITV4() asm volatile("s_waitcnt vmcnt(4)" ::: "memory")
#define WAITV8() asm volatile("s_waitcnt vmcnt(8)" ::: "memory")

__device__ __forceinline__ void gl_lds16(const void* g, void* l) {
  __builtin_amdgcn_global_load_lds((const __attribute__((address_space(1))) void*)g,
                                   (__attribute__((address_space(3))) void*)l, 16, 0, 0);
}

// Stage an 8-row chunk `c` of a [*][64] bf16 tile (global row stride `stride` elems)
// into LDS at lds + c*512, linear dest. XOR-swizzle applied on the GLOBAL source
// slot so that LDS[r][slot s] holds global slot s^(r&7).
__device__ __forceinline__ void stage64(const __hip_bfloat16* __restrict__ src, int stride,
                                        __hip_bfloat16* lds, int c, int l) {
  int r = c * 8 + (l >> 3);
  int cc = ((l & 7) ^ ((l >> 3) & 7)) * 8;
  gl_lds16(src + (size_t)r * stride + cc, lds + c * 512);
}

// 16x16x32 fragment: row `row`, k-slot ks*4+(l>>4).
__device__ __forceinline__ short8 frag64(const __hip_bfloat16* lds, int row, int ks, int l) {
  return *(const short8*)&lds[row * 64 + (((ks * 4 + (l >> 4)) ^ (row & 7)) * 8)];
}

// 32x32x16 fragment: row `row` (0..63), 16-wide k-chunk `subk` (0..3), elems
// k = subk*16 + (l>>5)*8 + 0..7.
__device__ __forceinline__ short8 frag32(const __hip_bfloat16* lds, int row, int subk, int l) {
  return *(const short8*)&lds[row * 64 + (((subk * 2 + (l >> 5)) ^ (row & 7)) * 8)];
}

// ---- convert x fp32 -> bf16 ----
__global__ __launch_bounds__(256) void k_cvt_x(const float* __restrict__ x,
                                               __hip_bfloat16* __restrict__ xb) {
  size_t i = ((size_t)blockIdx.x * 256 + threadIdx.x) * 4;
  float4 v = *(const float4*)(x + i);
  union { __hip_bfloat16 h[4]; short4 s; } u;
  u.h[0] = __float2bfloat16(v.x); u.h[1] = __float2bfloat16(v.y);
  u.h[2] = __float2bfloat16(v.z); u.h[3] = __float2bfloat16(v.w);
  *(short4*)(xb + i) = u.s;
}

// ---- transpose + convert W [k][c] fp32 -> Wt [c][k] bf16; z selects Q/K/V ----
__global__ void k_twb(const float* __restrict__ Wq, const float* __restrict__ Wk,
                      const float* __restrict__ Wv,
                      __hip_bfloat16* __restrict__ wtq, __hip_bfloat16* __restrict__ wtk,
                      __hip_bfloat16* __restrict__ wtv) {
  const float* W; __hip_bfloat16* Wt;
  if (blockIdx.z == 0)      { W = Wq; Wt = wtq; }
  else if (blockIdx.z == 1) { W = Wk; Wt = wtk; }
  else                      { W = Wv; Wt = wtv; }
  __shared__ float t[32][33];
  int tx = threadIdx.x, ty = threadIdx.y;
  int k0 = blockIdx.y * 32, c0 = blockIdx.x * 32;
#pragma unroll
  for (int i = 0; i < 4; ++i)
    t[ty + 8*i][tx] = W[(size_t)(k0 + ty + 8*i) * DOUT + c0 + tx];
  __syncthreads();
#pragma unroll
  for (int i = 0; i < 4; ++i)
    Wt[(size_t)(c0 + ty + 8*i) * DIN + k0 + tx] = __float2bfloat16(t[tx][ty + 8*i]);
}

// ---- QKV GEMM, BK=64, double-buffered, swizzled LDS, counted-vmcnt pipeline.
// q (z=0, pre-scaled by QSCALE), k (z=1): [b][h][s][d] ; v (z=2): [b][h][d][s] ----
__global__ __launch_bounds__(256) void k_qkv(
    const __hip_bfloat16* __restrict__ xb,
    const __hip_bfloat16* __restrict__ wq, const __hip_bfloat16* __restrict__ wk,
    const __hip_bfloat16* __restrict__ wv,
    __hip_bfloat16* __restrict__ qb, __hip_bfloat16* __restrict__ kb,
    __hip_bfloat16* __restrict__ vb) {
  __shared__ __hip_bfloat16 smem[32768];  // A0|A1|B0|B1, 8192 elems each (64KB)

  const __hip_bfloat16* wt; __hip_bfloat16* outp;
  if (blockIdx.z == 0)      { wt = wq; outp = qb; }
  else if (blockIdx.z == 1) { wt = wk; outp = kb; }
  else                      { wt = wv; outp = vb; }

  const int tid = threadIdx.x, w = tid >> 6, l = tid & 63;
  const int row0 = blockIdx.y * 128, col0 = blockIdx.x * 128;
  const int mw = (w >> 1) * 64, nw = (w & 1) * 64;

  const floatx4 fz = {0.f, 0.f, 0.f, 0.f};
  floatx4 acc[4][4];
#pragma unroll
  for (int m = 0; m < 4; ++m)
#pragma unroll
    for (int n = 0; n < 4; ++n) acc[m][n] = fz;

#pragma unroll
  for (int i = 0; i < 4; ++i) {
    stage64(xb + (size_t)row0 * DIN, DIN, smem, w*4+i, l);
    stage64(wt + (size_t)col0 * DIN, DIN, smem + 16384, w*4+i, l);
  }

  for (int kt = 0; kt < 16; ++kt) {
    int cur = kt & 1;
    __hip_bfloat16* Ac = smem + cur * 8192;
    __hip_bfloat16* Bc = smem + 16384 + cur * 8192;
    if (kt < 15) {
      int kk = (kt + 1) * 64;
      __hip_bfloat16* An = smem + (cur ^ 1) * 8192;
      __hip_bfloat16* Bn = smem + 16384 + (cur ^ 1) * 8192;
#pragma unroll
      for (int i = 0; i < 4; ++i) {
        stage64(xb + (size_t)row0 * DIN + kk, DIN, An, w*4+i, l);
        stage64(wt + (size_t)col0 * DIN + kk, DIN, Bn, w*4+i, l);
      }
      WAITV8();   // own loads for tile kt done; kt+1's 8 stay in flight
    } else {
      WAITV0();
    }
    SBAR();       // all waves' loads for tile kt landed
    short8 a[4][2], b[4][2];
#pragma unroll
    for (int m = 0; m < 4; ++m)
#pragma unroll
      for (int ks = 0; ks < 2; ++ks)
        a[m][ks] = frag64(Ac, mw + m*16 + (l & 15), ks, l);
#pragma unroll
    for (int n = 0; n < 4; ++n)
#pragma unroll
      for (int ks = 0; ks < 2; ++ks)
        b[n][ks] = frag64(Bc, nw + n*16 + (l & 15), ks, l);
#pragma unroll
    for (int ks = 0; ks < 2; ++ks)
#pragma unroll
      for (int m = 0; m < 4; ++m)
#pragma unroll
        for (int n = 0; n < 4; ++n)
          acc[m][n] = MFMA16(a[m][ks], b[n][ks], acc[m][n]);
    SBAR();       // reads of buf[cur] done before next iter's issue overwrites it
  }

  int bb2 = row0 >> 11, sbase = row0 & (SS - 1);
  if (blockIdx.z == 2) {
    // V: transpose through LDS (padded stride 136), then 16B coalesced stores.
    __hip_bfloat16* Vt2 = smem;
#pragma unroll
    for (int m = 0; m < 4; ++m)
#pragma unroll
      for (int n = 0; n < 4; ++n)
#pragma unroll
        for (int r4 = 0; r4 < 4; ++r4) {
          int r = mw + m*16 + ((l >> 4) << 2) + r4;
          int c = nw + n*16 + (l & 15);
          Vt2[c * 136 + r] = __float2bfloat16(acc[m][n][r4]);
        }
    __syncthreads();
#pragma unroll
    for (int i = 0; i < 8; ++i) {
      int drow = (tid >> 4) + i * 16;
      int scol = (tid & 15) * 8;
      int colg = col0 + drow, hh = colg >> 6, d = colg & 63;
      *(short8*)(outp + (((size_t)bb2 * NH + hh) * HD + d) * SS + sbase + scol) =
          *(const short8*)&Vt2[drow * 136 + scol];
    }
  } else {
    // Q/K: repack through LDS row-major [128][136], then 16B coalesced stores.
    float sc = (blockIdx.z == 0) ? QSCALE : 1.0f;
    __hip_bfloat16* T2 = smem;
#pragma unroll
    for (int m = 0; m < 4; ++m)
#pragma unroll
      for (int n = 0; n < 4; ++n)
#pragma unroll
        for (int r4 = 0; r4 < 4; ++r4) {
          int r = mw + m*16 + ((l >> 4) << 2) + r4;   // s-index in tile
          int c = nw + n*16 + (l & 15);               // d/head-col in tile
          T2[r * 136 + c] = __float2bfloat16(acc[m][n][r4] * sc);
        }
    __syncthreads();
#pragma unroll
    for (int i = 0; i < 8; ++i) {
      int r = (tid >> 4) + i * 16;          // 0..127 row (s)
      int c = (tid & 15) * 8;               // 0..120 col (d)
      int colg = col0 + c, hh = colg >> 6, d = colg & 63;
      *(short8*)(outp + (((size_t)bb2 * NH + hh) * SS + sbase + r) * HD + d) =
          *(const short8*)&T2[r * 136 + c];
    }
  }
}

// ---- pass A: Z[k] = sum_{q>=k} exp2(S'), then scale V columns by 1/Z in place.
// One j (64 k-columns) per block; grid (32 bh, 32 j), j ascending = longest
// first; 40KB LDS -> 3 blocks/CU co-resident. ----
__global__ __launch_bounds__(256) void k_cstat(const __hip_bfloat16* __restrict__ qb,
                                               const __hip_bfloat16* __restrict__ kb,
                                               __hip_bfloat16* __restrict__ vtb) {
  __shared__ __hip_bfloat16 smem[20480];  // Kt 4096 | Qt0 8192 | Qt1 8192 (40KB)
  __shared__ float red[4][64];
  __shared__ float zl[64];
  __hip_bfloat16* Kt = smem;
  const int bh = blockIdx.x;
  const int j = blockIdx.y;
  const int tid = threadIdx.x, w = tid >> 6, l = tid & 63;
  const int k0 = j * 64;
  const int t0 = j >> 1, niter = 16 - t0;

#pragma unroll
  for (int i = 0; i < 2; ++i)
    stage64(kb + ((size_t)bh * SS + k0) * HD, HD, Kt, w*2+i, l);
#pragma unroll
  for (int i = 0; i < 4; ++i)
    stage64(qb + ((size_t)bh * SS + (t0 << 7)) * HD, HD, smem + 4096, w*4+i, l);

  short8 kf[4][2];
  float csum[4] = {0.f, 0.f, 0.f, 0.f};
  for (int it = 0; it < niter; ++it) {
    int cur = it & 1;
    __hip_bfloat16* Qc = smem + 4096 + cur * 8192;
    int q0 = (t0 + it) << 7;
    if (it + 1 < niter) {
      __hip_bfloat16* Qn = smem + 4096 + (cur ^ 1) * 8192;
#pragma unroll
      for (int i = 0; i < 4; ++i)
        stage64(qb + ((size_t)bh * SS + q0 + 128) * HD, HD, Qn, w*4+i, l);
      WAITV4();   // K + Q(it) done; Q(it+1)'s 4 in flight
    } else {
      WAITV0();
    }
    SBAR();
    if (it == 0) {
#pragma unroll
      for (int n = 0; n < 4; ++n)
#pragma unroll
        for (int ks = 0; ks < 2; ++ks)
          kf[n][ks] = frag64(Kt, n*16 + (l & 15), ks, l);
    }
    int qw = q0 + w * 32;
    if (qw + 31 >= k0) {
      short8 qa[2][2];
#pragma unroll
      for (int mm = 0; mm < 2; ++mm)
#pragma unroll
        for (int ks = 0; ks < 2; ++ks)
          qa[mm][ks] = frag64(Qc, w*32 + mm*16 + (l & 15), ks, l);
      floatx4 s[2][4];
#pragma unroll
      for (int mm = 0; mm < 2; ++mm)
#pragma unroll
        for (int n = 0; n < 4; ++n) {
          floatx4 t = {0.f, 0.f, 0.f, 0.f};
#pragma unroll
          for (int ks = 0; ks < 2; ++ks) t = MFMA16(qa[mm][ks], kf[n][ks], t);
          s[mm][n] = t;
        }
      bool dia = (k0 + 63 > qw);
#pragma unroll
      for (int mm = 0; mm < 2; ++mm)
#pragma unroll
        for (int n = 0; n < 4; ++n)
#pragma unroll
          for (int r4 = 0; r4 < 4; ++r4) {
            float e = EXP2F(s[mm][n][r4]);
            if (dia) {
              int q = qw + mm*16 + ((l >> 4) << 2) + r4;
              int k = k0 + n*16 + (l & 15);
              if (k > q) e = 0.f;
            }
            csum[n] += e;
          }
    }
    SBAR();
  }

#pragma unroll
  for (int n = 0; n < 4; ++n) {
    csum[n] += __shfl_xor(csum[n], 16);
    csum[n] += __shfl_xor(csum[n], 32);
    if (l < 16) red[w][n*16 + l] = csum[n];
  }
  __syncthreads();
  if (tid < 64)
    zl[tid] = 1.0f / (red[0][tid] + red[1][tid] + red[2][tid] + red[3][tid]);
  __syncthreads();
  // scale vtb columns [k0, k0+64) by 1/Z (in place; disjoint per block)
#pragma unroll
  for (int i = 0; i < 4; ++i) {
    int d = (tid >> 4) + i * 16;
    int c = (tid & 15) * 4;
    size_t base = ((size_t)bh * HD + d) * SS + k0 + c;
    short4 v = *(const short4*)(vtb + base);
    __hip_bfloat16* hp = (__hip_bfloat16*)&v;
#pragma unroll
    for (int jv = 0; jv < 4; ++jv)
      hp[jv] = __float2bfloat16(__bfloat162float(hp[jv]) * zl[c + jv]);
    *(short4*)(vtb + base) = v;
  }
}

// ---- pass B: ctx[q,:] = sum_{k<=q} exp2(S') * Vs[k,:]  (Vs has 1/Z folded).
// K-SPLIT x4: 512 blocks x 16 waves (1024 thr). Block i: bh = i&31,
// tb = (i<256) ? 15-(i>>5) : (i-256)>>5. Wave w: row-group g = w&3 (rows
// Q0+g+4c, c=lane&31), k-quarter s = w>>2 (k-tiles s, s+4, ...). Private K/V
// dbuf per quarter: smem + s*16384 [K0|K1|V0|V1 x 4096 elems] = 128KB total.
// Partials: s>0 waves dump acc to LDS (aliases staging), s=0 adds and stores.
__global__ __launch_bounds__(1024, 4) void k_ctx(const __hip_bfloat16* __restrict__ qb,
                                                 const __hip_bfloat16* __restrict__ kb,
                                                 const __hip_bfloat16* __restrict__ vtb,
                                                 float* __restrict__ outp) {
  __shared__ __hip_bfloat16 smem[65536];  // 128KB
  const int i = blockIdx.x;
  const int bh = i & 31, bb = bh >> 4, h = bh & 15;
  const int tb = (i < 256) ? (15 - (i >> 5)) : ((i - 256) >> 5);
  const int Q0 = tb * 128;
  const int tid = threadIdx.x, w = tid >> 6, l = tid & 63;
  const int g = w & 3, s = w >> 2;
  const int hi = l >> 5;
  const int qg = Q0 + g + 4 * (l & 31);   // lane's q-row (ST column c = l&31)
  const int nkt = 2 * (tb + 1);           // 64-wide k-tiles in causal range
  const int nit = (nkt + 3) >> 2;         // loop count (uniform across waves)
  __hip_bfloat16* qsm = smem + s * 16384; // quarter's region: K0|K1|V0|V1

  // Q fragments: lane q-row = qg, elems d = hc*16 + hi*8 .. +7. Drain vmcnt in
  // the prologue so loop's counted waits only see staging ops.
  short8 qf[4];
  {
    const __hip_bfloat16* qrow = qb + ((size_t)bh * SS + qg) * HD + hi * 8;
#pragma unroll
    for (int hc = 0; hc < 4; ++hc)
      qf[hc] = *(const short8*)(qrow + hc * 16);
  }
  asm volatile("" :: "v"(qf[0]), "v"(qf[1]), "v"(qf[2]), "v"(qf[3]));
  WAITV0();

  // stage quarter's first k-tile (index s), 2 K-chunks + 2 V-chunks per wave
  if (s < nkt) {
    int kn = s << 6;
#pragma unroll
    for (int ii = 0; ii < 2; ++ii) {
      stage64(kb + ((size_t)bh * SS + kn) * HD, HD, qsm, g*2+ii, l);
      stage64(vtb + (size_t)bh * HD * SS + kn, SS, qsm + 8192, g*2+ii, l);
    }
  }

  const floatx16 fz16 = {0,0,0,0,0,0,0,0,0,0,0,0,0,0,0,0};
  floatx16 acc[2];
  acc[0] = fz16; acc[1] = fz16;

  for (int it = 0; it < nit; ++it) {
    int cur = it & 1;
    __hip_bfloat16* Kc = qsm + cur * 4096;
    __hip_bfloat16* Vc = qsm + 8192 + cur * 4096;
    const int myk = s + 4 * it;
    const int nxt = myk + 4;
    if (nxt < nkt) {
      int kn = nxt << 6;
#pragma unroll
      for (int ii = 0; ii < 2; ++ii) {
        stage64(kb + ((size_t)bh * SS + kn) * HD, HD, qsm + (cur^1) * 4096, g*2+ii, l);
        stage64(vtb + (size_t)bh * HD * SS + kn, SS, qsm + 8192 + (cur^1) * 4096, g*2+ii, l);
      }
      WAITV4();   // tile myk's 4 landed; nxt's 4 stay in flight
    } else {
      WAITV0();
    }
    SBAR();       // quarter's buf[cur] fully populated

    if (myk < nkt) {
      const int k0 = myk << 6;
      // ST halves: ST[k0+32H+roff][c], roff = (r&3)+8*(r>>2)+4*hi
      floatx16 st[2];
#pragma unroll
      for (int H = 0; H < 2; ++H) {
        floatx16 t = fz16;
#pragma unroll
        for (int hc = 0; hc < 4; ++hc)
          t = MFMA32(frag32(Kc, H*32 + (l & 31), hc, l), qf[hc], t);
        st[H] = t;
      }
      // exp2 + causal mask + pack to bf16 pairs: pk[H][m][pr] holds
      // k = k0 + 32H + 8m + 4hi + 2pr + {0,1}
      const bool dia = (k0 + 63 > Q0 + g);   // min q in wave = Q0 + g
      unsigned pk[2][4][2];
#pragma unroll
      for (int H = 0; H < 2; ++H)
#pragma unroll
        for (int m = 0; m < 4; ++m)
#pragma unroll
          for (int pr = 0; pr < 2; ++pr) {
            float e0 = EXP2F(st[H][m*4 + pr*2]);
            float e1 = EXP2F(st[H][m*4 + pr*2 + 1]);
            if (dia) {
              int kb0 = k0 + H*32 + m*8 + hi*4 + pr*2;
              if (kb0 > qg)     e0 = 0.f;
              if (kb0 + 1 > qg) e1 = 0.f;
            }
            pk[H][m][pr] = (unsigned)__bfloat16_as_ushort(__float2bfloat16(e0)) |
                           ((unsigned)__bfloat16_as_ushort(__float2bfloat16(e1)) << 16);
          }
      // PV: 4 k-chunks of 16; A-frag k = 16ks + hi*8 + 0..7.
#pragma unroll
      for (int ks = 0; ks < 4; ++ks) {
        const int H = ks >> 1, mb = (ks & 1) * 2;
        unsigned keep0 = hi ? pk[H][mb+1][0] : pk[H][mb][0];
        unsigned keep1 = hi ? pk[H][mb+1][1] : pk[H][mb][1];
        unsigned send0 = hi ? pk[H][mb][0]   : pk[H][mb+1][0];
        unsigned send1 = hi ? pk[H][mb][1]   : pk[H][mb+1][1];
        unsigned recv0 = (unsigned)__shfl_xor((int)send0, 32);
        unsigned recv1 = (unsigned)__shfl_xor((int)send1, 32);
        union { unsigned u[4]; short8 sv; } pa;
        pa.u[0] = hi ? recv0 : keep0;
        pa.u[1] = hi ? recv1 : keep1;
        pa.u[2] = hi ? keep0 : recv0;
        pa.u[3] = hi ? keep1 : recv1;
#pragma unroll
        for (int dn = 0; dn < 2; ++dn)
          acc[dn] = MFMA32(pa.sv, frag32(Vc, dn*32 + (l & 31), ks, l), acc[dn]);
      }
    }
    SBAR();       // reads of buf[cur] done before next iter overwrites it
  }

  // ---- reduce partials across k-quarters: acc_final[g] = sum_s acc[g][s] ----
  float* fsm = (float*)smem;   // staging dead after final SBAR; 32768 floats
  if (s > 0) {
    float* dst = fsm + ((s - 1) * 4 + g) * 2048;
#pragma unroll
    for (int dn = 0; dn < 2; ++dn)
#pragma unroll
      for (int r = 0; r < 16; ++r)
        dst[(dn * 16 + r) * 64 + l] = acc[dn][r];
  }
  __syncthreads();
  if (s == 0) {
#pragma unroll
    for (int sp = 0; sp < 3; ++sp) {
      const float* src = fsm + (sp * 4 + g) * 2048;
#pragma unroll
      for (int dn = 0; dn < 2; ++dn)
#pragma unroll
        for (int r = 0; r < 16; ++r)
          acc[dn][r] += src[(dn * 16 + r) * 64 + l];
    }
#pragma unroll
    for (int dn = 0; dn < 2; ++dn)
#pragma unroll
      for (int r = 0; r < 16; ++r) {
        int q = Q0 + g + 4 * ((r & 3) + 8*(r >> 2) + 4*hi);
        outp[((size_t)bb * SS + q) * DOUT + h * HD + dn*32 + (l & 31)] = acc[dn][r];
      }
  }
}

extern "C" void kernel_launch(void* const* d_in, const int* in_sizes, int n_in,
                              void* d_out, int out_size, void* d_ws, size_t ws_size,
                              hipStream_t stream) {
  const float* x  = (const float*)d_in[0];
  const float* Wq = (const float*)d_in[1];
  const float* Wk = (const float*)d_in[2];
  const float* Wv = (const float*)d_in[3];
  float* out = (float*)d_out;
  char* ws = (char*)d_ws;

  __hip_bfloat16* xb  = (__hip_bfloat16*)(ws);                   // 8 MB
  __hip_bfloat16* wtq = (__hip_bfloat16*)(ws + (8ull  << 20));   // 2 MB
  __hip_bfloat16* wtk = (__hip_bfloat16*)(ws + (10ull << 20));   // 2 MB
  __hip_bfloat16* wtv = (__hip_bfloat16*)(ws + (12ull << 20));   // 2 MB
  __hip_bfloat16* qb  = (__hip_bfloat16*)(ws + (14ull << 20));   // 8 MB [b][h][s][d], pre-scaled
  __hip_bfloat16* kb  = (__hip_bfloat16*)(ws + (22ull << 20));   // 8 MB [b][h][s][d]
  __hip_bfloat16* vtb = (__hip_bfloat16*)(ws + (30ull << 20));   // 8 MB [b][h][d][s], 1/Z folded

  k_cvt_x<<<4096, 256, 0, stream>>>(x, xb);
  dim3 tb(32, 8);
  k_twb<<<dim3(32, 32, 3), tb, 0, stream>>>(Wq, Wk, Wv, wtq, wtk, wtv);
  k_qkv<<<dim3(8, 32, 3), 256, 0, stream>>>(xb, wtq, wtk, wtv, qb, kb, vtb);
  k_cstat<<<dim3(32, 32), 256, 0, stream>>>(qb, kb, vtb);
  k_ctx<<<dim3(512), 1024, 0, stream>>>(qb, kb, vtb, out);
}